// Round 1
// baseline (251.971 us; speedup 1.0000x reference)
//
#include <hip/hip_runtime.h>
#include <math.h>

#define N_NODES 4096
#define IN_DIM  1433
#define HID     64
#define OUT_DIM 7
#define CAP     128     // max neighbors per node (avg 32, sigma ~5.6; 128 is >15 sigma)
#define KSPLIT  8
#define BR      128     // rows per gemm1 block
#define KT      32      // k-tile

static constexpr float LAMBDA = (float)(1.0 / 0.9 - 1.0);   // 0.11111111
static constexpr float SCADA  = 3.7f;

// ---------------------------------------------------------------------------
// Kernel 1: extract sparse adjacency + degrees from dense binary A (zero diag)
// ---------------------------------------------------------------------------
__global__ __launch_bounds__(256) void build_adj(const float* __restrict__ A,
    int* __restrict__ nbr, int* __restrict__ cnt, float* __restrict__ deg,
    float* __restrict__ rsd) {
  int i = blockIdx.x;
  __shared__ int c;
  if (threadIdx.x == 0) c = 0;
  __syncthreads();
  const float4* row = (const float4*)(A + (size_t)i * N_NODES);
  for (int q = threadIdx.x; q < N_NODES / 4; q += 256) {
    float4 v = row[q];
    int j0 = q * 4;
    if (v.x != 0.0f) { int s = atomicAdd(&c, 1); if (s < CAP) nbr[(size_t)i * CAP + s] = j0; }
    if (v.y != 0.0f) { int s = atomicAdd(&c, 1); if (s < CAP) nbr[(size_t)i * CAP + s] = j0 + 1; }
    if (v.z != 0.0f) { int s = atomicAdd(&c, 1); if (s < CAP) nbr[(size_t)i * CAP + s] = j0 + 2; }
    if (v.w != 0.0f) { int s = atomicAdd(&c, 1); if (s < CAP) nbr[(size_t)i * CAP + s] = j0 + 3; }
  }
  __syncthreads();
  if (threadIdx.x == 0) {
    int cc = c; if (cc > CAP) cc = CAP;
    cnt[i] = cc;
    float d = (float)c + 1.0f;      // + self loop
    deg[i] = d;
    rsd[i] = 1.0f / sqrtf(d);
  }
}

// ---------------------------------------------------------------------------
// Kernel 2: H_partial = X @ w1 (split-K, atomicAdd reduce). H must be zeroed.
// Block: 128 rows x 64 cols, 256 threads, each thread 8x4 register tile.
// Xs staged transposed with XOR swizzle (else 32-way LDS write conflict).
// ---------------------------------------------------------------------------
__global__ __launch_bounds__(256) void gemm1(const float* __restrict__ X,
    const float* __restrict__ w1, float* __restrict__ H) {
  __shared__ __align__(16) float Xs[KT][BR];
  __shared__ __align__(16) float Ws[KT][HID];
  const int t  = threadIdx.x;
  const int r0 = blockIdx.x * BR;
  const int ks = blockIdx.y;
  const int kbeg = (IN_DIM * ks) / KSPLIT;
  const int kend = (IN_DIM * (ks + 1)) / KSPLIT;
  const int rg = t >> 4;    // 0..15 -> rows rg*8 .. rg*8+7
  const int cg = t & 15;    // cols cg*4 .. cg*4+3

  float acc[8][4];
  #pragma unroll
  for (int r = 0; r < 8; ++r)
    #pragma unroll
    for (int c = 0; c < 4; ++c) acc[r][c] = 0.0f;

  for (int k0 = kbeg; k0 < kend; k0 += KT) {
    #pragma unroll
    for (int j = 0; j < (BR * KT) / 256; ++j) {   // 16 elems/thread
      int e = t + 256 * j;
      int row = e >> 5;           // e / KT
      int kk  = e & (KT - 1);
      int k   = k0 + kk;
      float v = (k < kend) ? X[(size_t)(r0 + row) * IN_DIM + k] : 0.0f;
      Xs[kk][row ^ ((kk & 7) * 4)] = v;           // swizzle: 4-way instead of 32-way
    }
    #pragma unroll
    for (int j = 0; j < (HID * KT) / 256; ++j) {  // 8 elems/thread
      int e = t + 256 * j;
      int kk  = e >> 6;
      int col = e & 63;
      int k   = k0 + kk;
      Ws[kk][col] = (k < kend) ? w1[(size_t)k * HID + col] : 0.0f;
    }
    __syncthreads();
    #pragma unroll
    for (int kk = 0; kk < KT; ++kk) {
      int sw = (kk & 7) * 4;
      const float4 xlo = *(const float4*)&Xs[kk][(rg * 8) ^ sw];      // rows rg*8..+3
      const float4 xhi = *(const float4*)&Xs[kk][(rg * 8 + 4) ^ sw];  // rows rg*8+4..+7
      const float4 wv  = *(const float4*)&Ws[kk][cg * 4];
      float xr[8] = {xlo.x, xlo.y, xlo.z, xlo.w, xhi.x, xhi.y, xhi.z, xhi.w};
      float wc[4] = {wv.x, wv.y, wv.z, wv.w};
      #pragma unroll
      for (int r = 0; r < 8; ++r)
        #pragma unroll
        for (int c = 0; c < 4; ++c) acc[r][c] += xr[r] * wc[c];
    }
    __syncthreads();
  }
  #pragma unroll
  for (int r = 0; r < 8; ++r) {
    int row = r0 + rg * 8 + r;
    #pragma unroll
    for (int c = 0; c < 4; ++c)
      atomicAdd(&H[(size_t)row * HID + cg * 4 + c], acc[r][c]);
  }
}

// ---------------------------------------------------------------------------
// Kernel 3: F0 = relu(H + b1) @ w2 + b2 ; also seed Fcur = F0
// ---------------------------------------------------------------------------
__global__ __launch_bounds__(256) void mlp_out(const float* __restrict__ H,
    const float* __restrict__ b1, const float* __restrict__ w2,
    const float* __restrict__ b2, float* __restrict__ F0, float* __restrict__ Fcur) {
  int t = blockIdx.x * blockDim.x + threadIdx.x;
  if (t >= N_NODES * OUT_DIM) return;
  int row = t / OUT_DIM, c = t % OUT_DIM;
  float acc = b2[c];
  const float* h = H + (size_t)row * HID;
  #pragma unroll
  for (int k = 0; k < HID; ++k) {
    float hv = fmaxf(h[k] + b1[k], 0.0f);
    acc += hv * w2[k * OUT_DIM + c];
  }
  F0[t] = acc;
  Fcur[t] = acc;
}

// ---------------------------------------------------------------------------
// Kernel 4: one RUNG propagation step. One wave (64 lanes) per node.
// ---------------------------------------------------------------------------
__global__ __launch_bounds__(256) void rung_step(const float* __restrict__ Fin,
    const float* __restrict__ F0, float* __restrict__ Fout,
    const int* __restrict__ nbr, const int* __restrict__ cnt,
    const float* __restrict__ deg, const float* __restrict__ rsd,
    const float* __restrict__ lg0p, const float* __restrict__ rdp, int kstep) {
  int wave = threadIdx.x >> 6;
  int lane = threadIdx.x & 63;
  int i = blockIdx.x * 4 + wave;

  // lam_k = exp(log_gamma_0) * sigmoid(raw_decay)^k / SCAD_A
  float r_ = 1.0f / (1.0f + expf(-rdp[0]));
  float rk = 1.0f;
  for (int q = 0; q < kstep; ++q) rk *= r_;
  float lam = expf(lg0p[0]) * rk * (1.0f / SCADA);

  float rsi = rsd[i];
  float Di  = deg[i];
  int   ci  = cnt[i];
  float Fi[OUT_DIM], Fni[OUT_DIM];
  #pragma unroll
  for (int c = 0; c < OUT_DIM; ++c) {
    Fi[c]  = Fin[(size_t)i * OUT_DIM + c];
    Fni[c] = Fi[c] * rsi;
  }
  float s = 0.0f;
  float acc[OUT_DIM] = {0, 0, 0, 0, 0, 0, 0};
  for (int l = lane; l < ci; l += 64) {
    int j = nbr[(size_t)i * CAP + l];
    float rsj = rsd[j];
    float fj[OUT_DIM];
    float d2 = 0.0f;
    #pragma unroll
    for (int c = 0; c < OUT_DIM; ++c) {
      fj[c] = Fin[(size_t)j * OUT_DIM + c];
      float df = Fni[c] - fj[c] * rsj;
      d2 += df * df;
    }
    float y = sqrtf(d2);
    float w;
    if (y <= lam)              w = 1.0f;
    else if (y <= SCADA * lam) w = (SCADA * lam - y) / ((SCADA - 1.0f) * fmaxf(y, 1e-12f));
    else                       w = 0.0f;
    if (w != w) w = 1.0f;      // NaN guard (matches reference)
    s += w;
    float wr = w * rsi * rsj;  // W_ij * A_tilde_ij
    #pragma unroll
    for (int c = 0; c < OUT_DIM; ++c) acc[c] += wr * fj[c];
  }
  // wave reduction
  #pragma unroll
  for (int off = 32; off > 0; off >>= 1) {
    s += __shfl_down(s, off);
    #pragma unroll
    for (int c = 0; c < OUT_DIM; ++c) acc[c] += __shfl_down(acc[c], off);
  }
  if (lane == 0) {
    float Q = s / Di + LAMBDA;
    float inv = 1.0f / Q;
    #pragma unroll
    for (int c = 0; c < OUT_DIM; ++c)
      Fout[(size_t)i * OUT_DIM + c] = (acc[c] + LAMBDA * F0[(size_t)i * OUT_DIM + c]) * inv;
  }
}

// ---------------------------------------------------------------------------
extern "C" void kernel_launch(void* const* d_in, const int* in_sizes, int n_in,
                              void* d_out, int out_size, void* d_ws, size_t ws_size,
                              hipStream_t stream) {
  const float* A   = (const float*)d_in[0];
  const float* X   = (const float*)d_in[1];
  const float* w1  = (const float*)d_in[2];
  const float* b1  = (const float*)d_in[3];
  const float* w2  = (const float*)d_in[4];
  const float* b2  = (const float*)d_in[5];
  const float* lg0 = (const float*)d_in[6];
  const float* rd  = (const float*)d_in[7];
  float* out = (float*)d_out;

  char* w = (char*)d_ws;
  int*   nbr = (int*)w;                    w += (size_t)N_NODES * CAP * sizeof(int);
  int*   cnt = (int*)w;                    w += (size_t)N_NODES * sizeof(int);
  float* deg = (float*)w;                  w += (size_t)N_NODES * sizeof(float);
  float* rsd = (float*)w;                  w += (size_t)N_NODES * sizeof(float);
  float* H   = (float*)w;                  w += (size_t)N_NODES * HID * sizeof(float);
  float* F0  = (float*)w;                  w += (size_t)N_NODES * OUT_DIM * sizeof(float);
  float* FA  = (float*)w;                  w += (size_t)N_NODES * OUT_DIM * sizeof(float);
  float* FB  = (float*)w;                  w += (size_t)N_NODES * OUT_DIM * sizeof(float);

  hipMemsetAsync(H, 0, (size_t)N_NODES * HID * sizeof(float), stream);
  build_adj<<<N_NODES, 256, 0, stream>>>(A, nbr, cnt, deg, rsd);
  gemm1<<<dim3(N_NODES / BR, KSPLIT), 256, 0, stream>>>(X, w1, H);
  mlp_out<<<(N_NODES * OUT_DIM + 255) / 256, 256, 0, stream>>>(H, b1, w2, b2, F0, FA);

  float* cur = FA;
  float* nxt = FB;
  for (int k = 0; k < 10; ++k) {
    float* dst = (k == 9) ? out : nxt;
    rung_step<<<N_NODES / 4, 256, 0, stream>>>(cur, F0, dst, nbr, cnt, deg, rsd, lg0, rd, k);
    float* tmp = cur; cur = nxt; nxt = tmp;
  }
}

// Round 2
// 227.455 us; speedup vs baseline: 1.1078x; 1.1078x over previous
//
#include <hip/hip_runtime.h>
#include <math.h>

#define N_NODES 4096
#define IN_DIM  1433
#define HID     64
#define OUT_DIM 7
#define FPAD    8       // padded feature stride for vectorized gathers
#define CAP     128     // max neighbors per node (avg 32, sigma 5.6; 128 >15 sigma)
#define KSPLIT  8
#define BR      128     // rows per gemm1 block
#define KT      32      // k-tile

static constexpr float LAMBDA = (float)(1.0 / 0.9 - 1.0);   // 0.11111111
static constexpr float SCADA  = 3.7f;

// ---------------------------------------------------------------------------
// Kernel 1: extract sparse adjacency + degrees from dense binary A (zero diag)
// ---------------------------------------------------------------------------
__global__ __launch_bounds__(256) void build_adj(const float* __restrict__ A,
    int* __restrict__ nbr, int* __restrict__ cnt, float* __restrict__ deg,
    float* __restrict__ rsd) {
  int i = blockIdx.x;
  __shared__ int c;
  if (threadIdx.x == 0) c = 0;
  __syncthreads();
  const float4* row = (const float4*)(A + (size_t)i * N_NODES);
  for (int q = threadIdx.x; q < N_NODES / 4; q += 256) {
    float4 v = row[q];
    int j0 = q * 4;
    if (v.x != 0.0f) { int s = atomicAdd(&c, 1); if (s < CAP) nbr[(size_t)i * CAP + s] = j0; }
    if (v.y != 0.0f) { int s = atomicAdd(&c, 1); if (s < CAP) nbr[(size_t)i * CAP + s] = j0 + 1; }
    if (v.z != 0.0f) { int s = atomicAdd(&c, 1); if (s < CAP) nbr[(size_t)i * CAP + s] = j0 + 2; }
    if (v.w != 0.0f) { int s = atomicAdd(&c, 1); if (s < CAP) nbr[(size_t)i * CAP + s] = j0 + 3; }
  }
  __syncthreads();
  if (threadIdx.x == 0) {
    int cc = c; if (cc > CAP) cc = CAP;
    cnt[i] = cc;
    float d = (float)c + 1.0f;      // + self loop
    deg[i] = d;
    rsd[i] = 1.0f / sqrtf(d);
  }
}

// ---------------------------------------------------------------------------
// Kernel 2: P[ks] = X[:, kchunk] @ w1[kchunk, :]  (split-K partials, NO atomics)
// Block: 128 rows x 64 cols, 256 threads, 8x4 register tile per thread.
// Xs transposed with +4 padding: b128-aligned, reads are 4-address broadcast.
// ---------------------------------------------------------------------------
__global__ __launch_bounds__(256) void gemm1(const float* __restrict__ X,
    const float* __restrict__ w1, float* __restrict__ P) {
  __shared__ __align__(16) float Xs[KT][BR + 4];   // stride 132 words: 16B-aligned rows
  __shared__ __align__(16) float Ws[KT][HID];
  const int t  = threadIdx.x;
  const int r0 = blockIdx.x * BR;
  const int ks = blockIdx.y;
  const int kbeg = (IN_DIM * ks) / KSPLIT;
  const int kend = (IN_DIM * (ks + 1)) / KSPLIT;
  const int rg = t >> 4;    // 0..15 -> rows rg*8 .. rg*8+7
  const int cg = t & 15;    // cols cg*4 .. cg*4+3

  float acc[8][4];
  #pragma unroll
  for (int r = 0; r < 8; ++r)
    #pragma unroll
    for (int c = 0; c < 4; ++c) acc[r][c] = 0.0f;

  for (int k0 = kbeg; k0 < kend; k0 += KT) {
    #pragma unroll
    for (int j = 0; j < (BR * KT) / 256; ++j) {   // 16 elems/thread
      int e = t + 256 * j;
      int row = e >> 5;           // e / KT
      int kk  = e & (KT - 1);
      int k   = k0 + kk;
      float v = (k < kend) ? X[(size_t)(r0 + row) * IN_DIM + k] : 0.0f;
      Xs[kk][row] = v;
    }
    #pragma unroll
    for (int j = 0; j < (HID * KT) / 256; ++j) {  // 8 elems/thread
      int e = t + 256 * j;
      int kk  = e >> 6;
      int col = e & 63;
      int k   = k0 + kk;
      Ws[kk][col] = (k < kend) ? w1[(size_t)k * HID + col] : 0.0f;
    }
    __syncthreads();
    #pragma unroll
    for (int kk = 0; kk < KT; ++kk) {
      const float4 xlo = *(const float4*)&Xs[kk][rg * 8];      // rows rg*8..+3 (broadcast x16)
      const float4 xhi = *(const float4*)&Xs[kk][rg * 8 + 4];  // rows rg*8+4..+7
      const float4 wv  = *(const float4*)&Ws[kk][cg * 4];      // cols (broadcast x4)
      float xr[8] = {xlo.x, xlo.y, xlo.z, xlo.w, xhi.x, xhi.y, xhi.z, xhi.w};
      float wc[4] = {wv.x, wv.y, wv.z, wv.w};
      #pragma unroll
      for (int r = 0; r < 8; ++r)
        #pragma unroll
        for (int c = 0; c < 4; ++c) acc[r][c] += xr[r] * wc[c];
    }
    __syncthreads();
  }
  float* Pp = P + (size_t)ks * N_NODES * HID;
  #pragma unroll
  for (int r = 0; r < 8; ++r) {
    int row = r0 + rg * 8 + r;
    float4 v = make_float4(acc[r][0], acc[r][1], acc[r][2], acc[r][3]);
    *(float4*)&Pp[(size_t)row * HID + cg * 4] = v;
  }
}

// ---------------------------------------------------------------------------
// Kernel 2b: H = sum over 8 split-K partials (vectorized float4)
// ---------------------------------------------------------------------------
__global__ __launch_bounds__(256) void reduce_h(const float* __restrict__ P,
    float* __restrict__ H) {
  int idx4 = blockIdx.x * 256 + threadIdx.x;          // 65536 float4 slots
  const float4* P4 = (const float4*)P;
  float4 s = P4[idx4];
  #pragma unroll
  for (int ks = 1; ks < KSPLIT; ++ks) {
    float4 v = P4[(size_t)ks * (N_NODES * HID / 4) + idx4];
    s.x += v.x; s.y += v.y; s.z += v.z; s.w += v.w;
  }
  ((float4*)H)[idx4] = s;
}

// ---------------------------------------------------------------------------
// Kernel 3: F0 = relu(H + b1) @ w2 + b2 ; seed Fcur = F0. Padded stride 8.
// ---------------------------------------------------------------------------
__global__ __launch_bounds__(256) void mlp_out(const float* __restrict__ H,
    const float* __restrict__ b1, const float* __restrict__ w2,
    const float* __restrict__ b2, float* __restrict__ F0, float* __restrict__ Fcur) {
  int t = blockIdx.x * blockDim.x + threadIdx.x;      // N*8 threads
  if (t >= N_NODES * FPAD) return;
  int row = t >> 3, c = t & 7;
  if (c == 7) { F0[t] = 0.0f; Fcur[t] = 0.0f; return; }
  float acc = b2[c];
  const float* h = H + (size_t)row * HID;
  #pragma unroll
  for (int k = 0; k < HID; ++k) {
    float hv = fmaxf(h[k] + b1[k], 0.0f);
    acc += hv * w2[k * OUT_DIM + c];
  }
  F0[t] = acc;
  Fcur[t] = acc;
}

// ---------------------------------------------------------------------------
// Kernel 4: one RUNG propagation step. One wave (64 lanes) per node.
// F stored padded [N][8] -> neighbor gather = 2x float4.
// ---------------------------------------------------------------------------
__global__ __launch_bounds__(256) void rung_step(const float* __restrict__ Fin,
    const float* __restrict__ F0, float* __restrict__ Fout,
    const int* __restrict__ nbr, const int* __restrict__ cnt,
    const float* __restrict__ deg, const float* __restrict__ rsd,
    const float* __restrict__ lg0p, const float* __restrict__ rdp,
    int kstep, int last) {
  int wave = threadIdx.x >> 6;
  int lane = threadIdx.x & 63;
  int i = blockIdx.x * 4 + wave;

  // lam_k = exp(log_gamma_0) * sigmoid(raw_decay)^k / SCAD_A
  float r_ = 1.0f / (1.0f + expf(-rdp[0]));
  float rk = 1.0f;
  for (int q = 0; q < kstep; ++q) rk *= r_;
  float lam = expf(lg0p[0]) * rk * (1.0f / SCADA);

  float rsi = rsd[i];
  float Di  = deg[i];
  int   ci  = cnt[i];
  float Fni[FPAD];
  {
    const float4* fp = (const float4*)(Fin + (size_t)i * FPAD);
    float4 a0 = fp[0], a1 = fp[1];
    Fni[0] = a0.x * rsi; Fni[1] = a0.y * rsi; Fni[2] = a0.z * rsi; Fni[3] = a0.w * rsi;
    Fni[4] = a1.x * rsi; Fni[5] = a1.y * rsi; Fni[6] = a1.z * rsi; Fni[7] = a1.w * rsi;
  }
  float s = 0.0f;
  float acc[FPAD] = {0, 0, 0, 0, 0, 0, 0, 0};
  for (int l = lane; l < ci; l += 64) {
    int j = nbr[(size_t)i * CAP + l];
    float rsj = rsd[j];
    const float4* fp = (const float4*)(Fin + (size_t)j * FPAD);
    float4 b0 = fp[0], b1v = fp[1];
    float fj[FPAD] = {b0.x, b0.y, b0.z, b0.w, b1v.x, b1v.y, b1v.z, b1v.w};
    float d2 = 0.0f;
    #pragma unroll
    for (int c = 0; c < FPAD; ++c) {
      float df = Fni[c] - fj[c] * rsj;
      d2 += df * df;
    }
    float y = sqrtf(d2);
    float w;
    if (y <= lam)              w = 1.0f;
    else if (y <= SCADA * lam) w = (SCADA * lam - y) / ((SCADA - 1.0f) * fmaxf(y, 1e-12f));
    else                       w = 0.0f;
    if (w != w) w = 1.0f;      // NaN guard (matches reference)
    s += w;
    float wr = w * rsi * rsj;  // W_ij * A_tilde_ij
    #pragma unroll
    for (int c = 0; c < FPAD; ++c) acc[c] += wr * fj[c];
  }
  // wave reduction
  #pragma unroll
  for (int off = 32; off > 0; off >>= 1) {
    s += __shfl_down(s, off);
    #pragma unroll
    for (int c = 0; c < FPAD; ++c) acc[c] += __shfl_down(acc[c], off);
  }
  if (lane == 0) {
    float Q = s / Di + LAMBDA;
    float inv = 1.0f / Q;
    if (last) {
      #pragma unroll
      for (int c = 0; c < OUT_DIM; ++c)
        Fout[(size_t)i * OUT_DIM + c] = (acc[c] + LAMBDA * F0[(size_t)i * FPAD + c]) * inv;
    } else {
      float o[FPAD];
      #pragma unroll
      for (int c = 0; c < FPAD; ++c)
        o[c] = (acc[c] + LAMBDA * F0[(size_t)i * FPAD + c]) * inv;   // pad col stays 0
      float4* op = (float4*)(Fout + (size_t)i * FPAD);
      op[0] = make_float4(o[0], o[1], o[2], o[3]);
      op[1] = make_float4(o[4], o[5], o[6], o[7]);
    }
  }
}

// ---------------------------------------------------------------------------
extern "C" void kernel_launch(void* const* d_in, const int* in_sizes, int n_in,
                              void* d_out, int out_size, void* d_ws, size_t ws_size,
                              hipStream_t stream) {
  const float* A   = (const float*)d_in[0];
  const float* X   = (const float*)d_in[1];
  const float* w1  = (const float*)d_in[2];
  const float* b1  = (const float*)d_in[3];
  const float* w2  = (const float*)d_in[4];
  const float* b2  = (const float*)d_in[5];
  const float* lg0 = (const float*)d_in[6];
  const float* rd  = (const float*)d_in[7];
  float* out = (float*)d_out;

  char* w = (char*)d_ws;
  int*   nbr = (int*)w;   w += (size_t)N_NODES * CAP * sizeof(int);
  int*   cnt = (int*)w;   w += (size_t)N_NODES * sizeof(int);
  float* deg = (float*)w; w += (size_t)N_NODES * sizeof(float);
  float* rsd = (float*)w; w += (size_t)N_NODES * sizeof(float);
  float* P   = (float*)w; w += (size_t)KSPLIT * N_NODES * HID * sizeof(float);
  float* H   = (float*)w; w += (size_t)N_NODES * HID * sizeof(float);
  float* F0  = (float*)w; w += (size_t)N_NODES * FPAD * sizeof(float);
  float* FA  = (float*)w; w += (size_t)N_NODES * FPAD * sizeof(float);
  float* FB  = (float*)w; w += (size_t)N_NODES * FPAD * sizeof(float);

  build_adj<<<N_NODES, 256, 0, stream>>>(A, nbr, cnt, deg, rsd);
  gemm1<<<dim3(N_NODES / BR, KSPLIT), 256, 0, stream>>>(X, w1, P);
  reduce_h<<<(N_NODES * HID / 4) / 256, 256, 0, stream>>>(P, H);
  mlp_out<<<(N_NODES * FPAD) / 256, 256, 0, stream>>>(H, b1, w2, b2, F0, FA);

  float* cur = FA;
  float* nxt = FB;
  for (int k = 0; k < 10; ++k) {
    int last = (k == 9);
    float* dst = last ? out : nxt;
    rung_step<<<N_NODES / 4, 256, 0, stream>>>(cur, F0, dst, nbr, cnt, deg, rsd,
                                               lg0, rd, k, last);
    float* tmp = cur; cur = nxt; nxt = tmp;
  }
}